// Round 1
// baseline (58.790 us; speedup 1.0000x reference)
//
#include <hip/hip_runtime.h>

// Perceptual color difference (CIELAB, lightness_weight = 0).
// Inputs: img1, img2 : (B=32, C=3, H=512, W=512) float32, NCHW.
// Output: per-batch mean over HxW of sqrt(da^2 + db^2), 32 floats.

#define HW (512 * 512)          // pixels per channel plane
#define NB 32                   // batch
#define BLOCKS_PER_BATCH 64
#define THREADS 256

__device__ __forceinline__ float srgb_lin(float c) {
    // where(c <= 0.04045, c/12.92, ((c+0.055)/1.055)^2.4)
    if (c <= 0.04045f) return c * (1.0f / 12.92f);
    float t = (c + 0.055f) * (1.0f / 1.055f);
    return exp2f(2.4f * log2f(t));
}

__device__ __forceinline__ float lab_f(float t) {
    // where(t > delta^3, cbrt(t), t/(3*delta^2) + 4/29), delta = 6/29
    const float d3 = 0.008856451679035631f;       // (6/29)^3
    if (t > d3) return exp2f((1.0f / 3.0f) * log2f(t));
    return t * 7.787037037037037f + (4.0f / 29.0f); // 1/(3*(6/29)^2) = 841/108
}

__device__ __forceinline__ void rgb_to_ab(float r, float g, float b,
                                          float& a_out, float& b_out) {
    float lr = srgb_lin(r), lg = srgb_lin(g), lb = srgb_lin(b);
    float x = 0.4124564f * lr + 0.3575761f * lg + 0.1804375f * lb;
    float y = 0.2126729f * lr + 0.7151522f * lg + 0.0721750f * lb;
    float z = 0.0193339f * lr + 0.1191920f * lg + 0.9503041f * lb;
    float fx = lab_f(x * (1.0f / 0.95047f));
    float fy = lab_f(y);                  // white[1] = 1.0
    float fz = lab_f(z * (1.0f / 1.08883f));
    a_out = 500.0f * (fx - fy);
    b_out = 200.0f * (fy - fz);
}

// Stage 1: per-(batch, block) partial sums of the cd map.
__global__ __launch_bounds__(THREADS) void cd_partial(
    const float* __restrict__ img1, const float* __restrict__ img2,
    float* __restrict__ ws) {
    const int b = blockIdx.y;
    const size_t base = (size_t)b * 3 * HW;
    const float4* __restrict__ p1 = (const float4*)(img1 + base);
    const float4* __restrict__ p2 = (const float4*)(img2 + base);
    const int nvec = HW / 4;       // 65536 float4 per plane
    const int coff = HW / 4;       // plane stride in float4

    float sum = 0.0f;
    for (int i = blockIdx.x * blockDim.x + threadIdx.x; i < nvec;
         i += gridDim.x * blockDim.x) {
        float4 r1 = p1[i];
        float4 g1 = p1[i + coff];
        float4 u1 = p1[i + 2 * coff];
        float4 r2 = p2[i];
        float4 g2 = p2[i + coff];
        float4 u2 = p2[i + 2 * coff];
        const float* fr1 = (const float*)&r1;
        const float* fg1 = (const float*)&g1;
        const float* fu1 = (const float*)&u1;
        const float* fr2 = (const float*)&r2;
        const float* fg2 = (const float*)&g2;
        const float* fu2 = (const float*)&u2;
#pragma unroll
        for (int k = 0; k < 4; ++k) {
            float a1, c1, a2, c2;
            rgb_to_ab(fr1[k], fg1[k], fu1[k], a1, c1);
            rgb_to_ab(fr2[k], fg2[k], fu2[k], a2, c2);
            float da = a1 - a2;
            float db = c1 - c2;
            sum += sqrtf(da * da + db * db);
        }
    }

    // wave64 reduce
#pragma unroll
    for (int off = 32; off > 0; off >>= 1) sum += __shfl_down(sum, off);

    __shared__ float ssum[THREADS / 64];
    const int lane = threadIdx.x & 63;
    const int wid = threadIdx.x >> 6;
    if (lane == 0) ssum[wid] = sum;
    __syncthreads();
    if (threadIdx.x == 0) {
        float s = 0.0f;
#pragma unroll
        for (int w = 0; w < THREADS / 64; ++w) s += ssum[w];
        ws[(size_t)b * gridDim.x + blockIdx.x] = s;
    }
}

// Stage 2: reduce BLOCKS_PER_BATCH partials per batch, divide by HW.
__global__ __launch_bounds__(64) void cd_final(
    const float* __restrict__ ws, float* __restrict__ out) {
    const int b = blockIdx.x;
    float s = ws[(size_t)b * BLOCKS_PER_BATCH + threadIdx.x];
#pragma unroll
    for (int off = 32; off > 0; off >>= 1) s += __shfl_down(s, off);
    if (threadIdx.x == 0) out[b] = s * (1.0f / (float)HW);
}

extern "C" void kernel_launch(void* const* d_in, const int* in_sizes, int n_in,
                              void* d_out, int out_size, void* d_ws, size_t ws_size,
                              hipStream_t stream) {
    const float* img1 = (const float*)d_in[0];
    const float* img2 = (const float*)d_in[1];
    float* out = (float*)d_out;
    float* ws = (float*)d_ws;   // needs NB * BLOCKS_PER_BATCH * 4 = 8 KB

    dim3 grid1(BLOCKS_PER_BATCH, NB);
    cd_partial<<<grid1, THREADS, 0, stream>>>(img1, img2, ws);
    cd_final<<<NB, 64, 0, stream>>>(ws, out);
}

// Round 4
// 58.393 us; speedup vs baseline: 1.0068x; 1.0068x over previous
//
#include <hip/hip_runtime.h>

// Perceptual color difference (CIELAB, lightness_weight = 0).
// Inputs: img1, img2 : (B=32, C=3, H=512, W=512) float32, NCHW.
// Output: per-batch mean over HxW of sqrt(da^2 + db^2), 32 floats.
//
// Round 4: keep round-2 algebra (gamma scale folded into RGB->XYZ matrix,
// white point folded into the a/b linear combination), but express packed
// math as plain ext_vector_type(2) C arithmetic (backend emits v_pk_*_f32
// itself on gfx950) and use proven exp2f/log2f (v_exp_f32/v_log_f32).
//
// Constant derivation:
//  K   = 1.055^-2.4 = 0.87941365  (folded: M' = K*M, so gamma branch is
//        (c+0.055)^2.4 with no divide)
//  CS1 = 1/(12.92*K) = 0.08801236 (linear-branch scale, pre-matrix)
//  cx  = 0.95047^-1/3 = 1.0170883 ; cz = 1.08883^-1/3 = 0.9720339
//  fx = cx*cbrt(x), etc.; a = 500*(fx-fy) = 508.54415*sx - 500*sy
//  b = 200*(fy-fz) = 200*sy - 194.40678*sz  (s* = cbrt of folded xyz)
//  linear lab branch: A* = 7.787037/(w* * c*), B* = (4/29)/c*
//  thresholds: x > (6/29)^3 * w*

typedef float v2f __attribute__((ext_vector_type(2)));
typedef float v4f __attribute__((ext_vector_type(4)));

#define HW (512 * 512)
#define NB 32
#define BPB 128                  // blocks per batch
#define THREADS 256
#define STRIDE (BPB * THREADS)   // 32768 float4; nvec = 65536 = 2*STRIDE

__device__ __forceinline__ v2f v2exp2(v2f x) {
    v2f r; r.x = exp2f(x.x); r.y = exp2f(x.y); return r;
}
__device__ __forceinline__ v2f v2log2(v2f x) {
    v2f r; r.x = log2f(x.x); r.y = log2f(x.y); return r;
}

__device__ __forceinline__ v2f srgb2(v2f c) {
    v2f p = v2exp2(v2log2(c + 0.055f) * 2.4f);
    v2f lo = c * 0.08801236f;
    v2f r;
    r.x = (c.x <= 0.04045f) ? lo.x : p.x;
    r.y = (c.y <= 0.04045f) ? lo.y : p.y;
    return r;
}

__device__ __forceinline__ v2f labf2(v2f x, float A, float B, float thr) {
    v2f g = v2exp2(v2log2(x) * (1.0f / 3.0f));
    v2f lo = x * A + B;
    v2f r;
    r.x = (x.x > thr) ? g.x : lo.x;
    r.y = (x.y > thr) ? g.y : lo.y;
    return r;
}

__device__ __forceinline__ void pipe(v2f r, v2f g, v2f u, v2f& apk, v2f& bpk) {
    v2f lr = srgb2(r), lg = srgb2(g), lb = srgb2(u);
    v2f x = lr * 0.3627198f + lg * 0.3144573f + lb * 0.1586792f;
    v2f y = lr * 0.1870275f + lg * 0.6289146f + lb * 0.0634717f;
    v2f z = lr * 0.0170025f + lg * 0.1048191f + lb * 0.8357104f;
    v2f sx = labf2(x, 8.0551810f, 0.13561340f, 0.008417790f);
    v2f sy = labf2(y, 7.7870370f, 0.13793103f, 0.008856452f);
    v2f sz = labf2(z, 7.3575050f, 0.14189940f, 0.009643159f);
    apk = sx * 508.54415f - sy * 500.0f;
    bpk = sy * 200.0f - sz * 194.40678f;
}

__global__ __launch_bounds__(THREADS) void cd_partial(
    const float* __restrict__ img1, const float* __restrict__ img2,
    float* __restrict__ ws) {
    const int b = blockIdx.y;
    const size_t base = (size_t)b * 3 * HW;
    const v4f* __restrict__ p1 = (const v4f*)(img1 + base);
    const v4f* __restrict__ p2 = (const v4f*)(img2 + base);
    const int coff = HW / 4;

    float sum = 0.0f;
    const int i0 = blockIdx.x * THREADS + threadIdx.x;

#pragma unroll
    for (int chunk = 0; chunk < 2; ++chunk) {
        const int i = i0 + chunk * STRIDE;
        v4f r1 = p1[i], g1 = p1[i + coff], u1 = p1[i + 2 * coff];
        v4f r2 = p2[i], g2 = p2[i + coff], u2 = p2[i + 2 * coff];
#pragma unroll
        for (int h = 0; h < 2; ++h) {
            v2f R1 = h ? __builtin_shufflevector(r1, r1, 2, 3) : __builtin_shufflevector(r1, r1, 0, 1);
            v2f G1 = h ? __builtin_shufflevector(g1, g1, 2, 3) : __builtin_shufflevector(g1, g1, 0, 1);
            v2f U1 = h ? __builtin_shufflevector(u1, u1, 2, 3) : __builtin_shufflevector(u1, u1, 0, 1);
            v2f R2 = h ? __builtin_shufflevector(r2, r2, 2, 3) : __builtin_shufflevector(r2, r2, 0, 1);
            v2f G2 = h ? __builtin_shufflevector(g2, g2, 2, 3) : __builtin_shufflevector(g2, g2, 0, 1);
            v2f U2 = h ? __builtin_shufflevector(u2, u2, 2, 3) : __builtin_shufflevector(u2, u2, 0, 1);
            v2f a1, b1, a2, b2;
            pipe(R1, G1, U1, a1, b1);
            pipe(R2, G2, U2, a2, b2);
            v2f da = a1 - a2;
            v2f db = b1 - b2;
            v2f e = da * da + db * db;
            sum += sqrtf(e.x) + sqrtf(e.y);
        }
    }

    // wave64 reduce
#pragma unroll
    for (int off = 32; off > 0; off >>= 1) sum += __shfl_down(sum, off);

    __shared__ float ssum[THREADS / 64];
    const int lane = threadIdx.x & 63;
    const int wid = threadIdx.x >> 6;
    if (lane == 0) ssum[wid] = sum;
    __syncthreads();
    if (threadIdx.x == 0) {
        float s = 0.0f;
#pragma unroll
        for (int w = 0; w < THREADS / 64; ++w) s += ssum[w];
        ws[(size_t)b * BPB + blockIdx.x] = s;
    }
}

// Stage 2: reduce BPB partials per batch, divide by HW.
__global__ __launch_bounds__(64) void cd_final(
    const float* __restrict__ ws, float* __restrict__ out) {
    const int b = blockIdx.x;
    float s = ws[(size_t)b * BPB + threadIdx.x] +
              ws[(size_t)b * BPB + threadIdx.x + 64];
#pragma unroll
    for (int off = 32; off > 0; off >>= 1) s += __shfl_down(s, off);
    if (threadIdx.x == 0) out[b] = s * (1.0f / (float)HW);
}

extern "C" void kernel_launch(void* const* d_in, const int* in_sizes, int n_in,
                              void* d_out, int out_size, void* d_ws, size_t ws_size,
                              hipStream_t stream) {
    const float* img1 = (const float*)d_in[0];
    const float* img2 = (const float*)d_in[1];
    float* out = (float*)d_out;
    float* ws = (float*)d_ws;   // NB * BPB * 4 = 16 KB

    dim3 grid1(BPB, NB);
    cd_partial<<<grid1, THREADS, 0, stream>>>(img1, img2, ws);
    cd_final<<<NB, 64, 0, stream>>>(ws, out);
}

// Round 5
// 38.820 us; speedup vs baseline: 1.5144x; 1.5042x over previous
//
#include <hip/hip_runtime.h>

// Perceptual color difference (CIELAB, lightness_weight = 0).
// Inputs: img1, img2 : (B=32, C=3, H=512, W=512) float32, NCHW.
// Output: per-batch mean over HxW of sqrt(da^2 + db^2), 32 floats.
//
// Round 5: identical to round 4 (passing, absmax 0.0) except transcendentals
// now use native hardware instructions via builtins instead of OCML libm:
//   __builtin_amdgcn_logf  -> v_log_f32  (log2, ~1 ulp)
//   __builtin_amdgcn_exp2f -> v_exp_f32  (2^x,  ~1 ulp)
//   __builtin_amdgcn_sqrtf -> v_sqrt_f32
// (The harness compiles without -ffast-math, so exp2f/log2f/sqrtf were
//  multi-instruction __ocml_* software routines — the round-1/4 bottleneck.)
//
// Constant derivation:
//  K   = 1.055^-2.4 = 0.87941365  (folded: M' = K*M, so gamma branch is
//        (c+0.055)^2.4 with no divide)
//  CS1 = 1/(12.92*K) = 0.08801236 (linear-branch scale, pre-matrix)
//  cx  = 0.95047^-1/3 = 1.0170883 ; cz = 1.08883^-1/3 = 0.9720339
//  fx = cx*cbrt(x), etc.; a = 500*(fx-fy) = 508.54415*sx - 500*sy
//  b = 200*(fy-fz) = 200*sy - 194.40678*sz  (s* = cbrt of folded xyz)
//  linear lab branch: A* = 7.787037/(w* * c*), B* = (4/29)/c*
//  thresholds: x > (6/29)^3 * w*

typedef float v2f __attribute__((ext_vector_type(2)));
typedef float v4f __attribute__((ext_vector_type(4)));

#define HW (512 * 512)
#define NB 32
#define BPB 128                  // blocks per batch
#define THREADS 256
#define STRIDE (BPB * THREADS)   // 32768 float4; nvec = 65536 = 2*STRIDE

__device__ __forceinline__ v2f v2exp2(v2f x) {
    v2f r;
    r.x = __builtin_amdgcn_exp2f(x.x);
    r.y = __builtin_amdgcn_exp2f(x.y);
    return r;
}
__device__ __forceinline__ v2f v2log2(v2f x) {
    v2f r;
    r.x = __builtin_amdgcn_logf(x.x);
    r.y = __builtin_amdgcn_logf(x.y);
    return r;
}

__device__ __forceinline__ v2f srgb2(v2f c) {
    v2f p = v2exp2(v2log2(c + 0.055f) * 2.4f);
    v2f lo = c * 0.08801236f;
    v2f r;
    r.x = (c.x <= 0.04045f) ? lo.x : p.x;
    r.y = (c.y <= 0.04045f) ? lo.y : p.y;
    return r;
}

__device__ __forceinline__ v2f labf2(v2f x, float A, float B, float thr) {
    v2f g = v2exp2(v2log2(x) * (1.0f / 3.0f));
    v2f lo = x * A + B;
    v2f r;
    r.x = (x.x > thr) ? g.x : lo.x;
    r.y = (x.y > thr) ? g.y : lo.y;
    return r;
}

__device__ __forceinline__ void pipe(v2f r, v2f g, v2f u, v2f& apk, v2f& bpk) {
    v2f lr = srgb2(r), lg = srgb2(g), lb = srgb2(u);
    v2f x = lr * 0.3627198f + lg * 0.3144573f + lb * 0.1586792f;
    v2f y = lr * 0.1870275f + lg * 0.6289146f + lb * 0.0634717f;
    v2f z = lr * 0.0170025f + lg * 0.1048191f + lb * 0.8357104f;
    v2f sx = labf2(x, 8.0551810f, 0.13561340f, 0.008417790f);
    v2f sy = labf2(y, 7.7870370f, 0.13793103f, 0.008856452f);
    v2f sz = labf2(z, 7.3575050f, 0.14189940f, 0.009643159f);
    apk = sx * 508.54415f - sy * 500.0f;
    bpk = sy * 200.0f - sz * 194.40678f;
}

__global__ __launch_bounds__(THREADS) void cd_partial(
    const float* __restrict__ img1, const float* __restrict__ img2,
    float* __restrict__ ws) {
    const int b = blockIdx.y;
    const size_t base = (size_t)b * 3 * HW;
    const v4f* __restrict__ p1 = (const v4f*)(img1 + base);
    const v4f* __restrict__ p2 = (const v4f*)(img2 + base);
    const int coff = HW / 4;

    float sum = 0.0f;
    const int i0 = blockIdx.x * THREADS + threadIdx.x;

#pragma unroll
    for (int chunk = 0; chunk < 2; ++chunk) {
        const int i = i0 + chunk * STRIDE;
        v4f r1 = p1[i], g1 = p1[i + coff], u1 = p1[i + 2 * coff];
        v4f r2 = p2[i], g2 = p2[i + coff], u2 = p2[i + 2 * coff];
#pragma unroll
        for (int h = 0; h < 2; ++h) {
            v2f R1 = h ? __builtin_shufflevector(r1, r1, 2, 3) : __builtin_shufflevector(r1, r1, 0, 1);
            v2f G1 = h ? __builtin_shufflevector(g1, g1, 2, 3) : __builtin_shufflevector(g1, g1, 0, 1);
            v2f U1 = h ? __builtin_shufflevector(u1, u1, 2, 3) : __builtin_shufflevector(u1, u1, 0, 1);
            v2f R2 = h ? __builtin_shufflevector(r2, r2, 2, 3) : __builtin_shufflevector(r2, r2, 0, 1);
            v2f G2 = h ? __builtin_shufflevector(g2, g2, 2, 3) : __builtin_shufflevector(g2, g2, 0, 1);
            v2f U2 = h ? __builtin_shufflevector(u2, u2, 2, 3) : __builtin_shufflevector(u2, u2, 0, 1);
            v2f a1, b1, a2, b2;
            pipe(R1, G1, U1, a1, b1);
            pipe(R2, G2, U2, a2, b2);
            v2f da = a1 - a2;
            v2f db = b1 - b2;
            v2f e = da * da + db * db;
            sum += __builtin_amdgcn_sqrtf(e.x) + __builtin_amdgcn_sqrtf(e.y);
        }
    }

    // wave64 reduce
#pragma unroll
    for (int off = 32; off > 0; off >>= 1) sum += __shfl_down(sum, off);

    __shared__ float ssum[THREADS / 64];
    const int lane = threadIdx.x & 63;
    const int wid = threadIdx.x >> 6;
    if (lane == 0) ssum[wid] = sum;
    __syncthreads();
    if (threadIdx.x == 0) {
        float s = 0.0f;
#pragma unroll
        for (int w = 0; w < THREADS / 64; ++w) s += ssum[w];
        ws[(size_t)b * BPB + blockIdx.x] = s;
    }
}

// Stage 2: reduce BPB partials per batch, divide by HW.
__global__ __launch_bounds__(64) void cd_final(
    const float* __restrict__ ws, float* __restrict__ out) {
    const int b = blockIdx.x;
    float s = ws[(size_t)b * BPB + threadIdx.x] +
              ws[(size_t)b * BPB + threadIdx.x + 64];
#pragma unroll
    for (int off = 32; off > 0; off >>= 1) s += __shfl_down(s, off);
    if (threadIdx.x == 0) out[b] = s * (1.0f / (float)HW);
}

extern "C" void kernel_launch(void* const* d_in, const int* in_sizes, int n_in,
                              void* d_out, int out_size, void* d_ws, size_t ws_size,
                              hipStream_t stream) {
    const float* img1 = (const float*)d_in[0];
    const float* img2 = (const float*)d_in[1];
    float* out = (float*)d_out;
    float* ws = (float*)d_ws;   // NB * BPB * 4 = 16 KB

    dim3 grid1(BPB, NB);
    cd_partial<<<grid1, THREADS, 0, stream>>>(img1, img2, ws);
    cd_final<<<NB, 64, 0, stream>>>(ws, out);
}